// Round 4
// baseline (308.017 us; speedup 1.0000x reference)
//
#include <hip/hip_runtime.h>

#define NN 100000
#define NE 1600000
#define IC 128
#define HID 32
#define NB 782          // buckets of 128 nodes
#define EB 4096         // edges per binning block
#define NBA 391         // ceil(NE/EB)

typedef unsigned short ushort_t;

__device__ __forceinline__ ushort_t f2bf(float x) {
    unsigned u = __float_as_uint(x);
    unsigned r = (u + 0x7fffu + ((u >> 16) & 1u)) >> 16;   // round-to-nearest-even
    return (ushort_t)r;
}
__device__ __forceinline__ float bf2f(ushort_t b) {
    return __uint_as_float(((unsigned)b) << 16);
}

// ---------------- edge dtype detection ----------------
__global__ void detect_kernel(const void* ei, int* flag) {
    const long long* p = (const long long*)ei;
    int ok = 1;
    for (int i = 0; i < 64; i++) {
        long long v = p[i];
        if (v < 0 || v >= NN) ok = 0;
    }
    *flag = ok;
}

__device__ __forceinline__ int edge_at(const void* ei, int i64f, long long idx) {
    return i64f ? (int)((const long long*)ei)[idx] : ((const int*)ei)[idx];
}

__global__ void zero_kernel(int* bucketCnt) {
    int t = threadIdx.x;
    if (t < NB) bucketCnt[t] = 0;
}

// Fold w1b@w2a, b1b@w2a, w2b@w3, b2b@w3.
__global__ void precompute_kernel(const float* __restrict__ w1b, const float* __restrict__ b1b,
                                  const float* __restrict__ w2a, const float* __restrict__ w2b,
                                  const float* __restrict__ b2b, const float* __restrict__ w3,
                                  float* Wc, float* bc1, float* wc2, float* c0) {
    int t = threadIdx.x;           // 1024 threads
    int k = t >> 5, j = t & 31;
    float acc = 0.f;
    for (int m = 0; m < HID; m++) acc += w1b[k * HID + m] * w2a[m * HID + j];
    Wc[k * HID + j] = acc;
    if (t < 32) {
        float a = 0.f;
        for (int m = 0; m < HID; m++) a += b1b[m] * w2a[m * HID + t];
        bc1[t] = a;
    } else if (t < 64) {
        int kk = t - 32;
        float a = 0.f;
        for (int jj = 0; jj < HID; jj++) a += w2b[kk * HID + jj] * w3[jj];
        wc2[kk] = a;
    } else if (t == 64) {
        float a = 0.f;
        for (int jj = 0; jj < HID; jj++) a += b2b[jj] * w3[jj];
        *c0 = a;
    }
}

// ---------------- proj1: y1 = x @ w1a, output bf16 feature-split ----------------
__global__ __launch_bounds__(256) void proj1_kernel(const float* __restrict__ x,
                                                    const float* __restrict__ w1a,
                                                    ushort_t* __restrict__ y1lo,
                                                    ushort_t* __restrict__ y1hi) {
    __shared__ float xs[64 * 132];
    __shared__ float ws[IC * HID];
    int t = threadIdx.x;
    int base = blockIdx.x * 64;

    #pragma unroll
    for (int i = 0; i < 16; i++) ws[i * 256 + t] = w1a[i * 256 + t];

    const float4* xg = (const float4*)x;
    #pragma unroll
    for (int i = 0; i < 8; i++) {
        int fi = i * 256 + t;
        int row = fi >> 5;
        int kq = fi & 31;
        float4 v = make_float4(0.f, 0.f, 0.f, 0.f);
        if (base + row < NN) v = xg[(size_t)(base + row) * 32 + kq];
        *(float4*)&xs[row * 132 + kq * 4] = v;
    }
    __syncthreads();

    int ng = t >> 3;
    int fg = t & 7;
    int n0 = ng * 2, n1 = n0 + 1;
    int j0 = fg * 4;
    float4 a0 = make_float4(0.f, 0.f, 0.f, 0.f);
    float4 a1 = make_float4(0.f, 0.f, 0.f, 0.f);
    #pragma unroll 8
    for (int k = 0; k < IC; k++) {
        float x0 = xs[n0 * 132 + k];
        float x1 = xs[n1 * 132 + k];
        float4 w = *(const float4*)&ws[k * HID + j0];
        a0.x += x0 * w.x; a0.y += x0 * w.y; a0.z += x0 * w.z; a0.w += x0 * w.w;
        a1.x += x1 * w.x; a1.y += x1 * w.y; a1.z += x1 * w.z; a1.w += x1 * w.w;
    }
    ushort4 p0, p1;
    p0.x = f2bf(a0.x); p0.y = f2bf(a0.y); p0.z = f2bf(a0.z); p0.w = f2bf(a0.w);
    p1.x = f2bf(a1.x); p1.y = f2bf(a1.y); p1.z = f2bf(a1.z); p1.w = f2bf(a1.w);
    ushort_t* dst = (fg < 4) ? y1lo : y1hi;
    int col = (fg < 4) ? j0 : (j0 - 16);
    if (base + n0 < NN) *(ushort4*)&dst[(size_t)(base + n0) * 16 + col] = p0;
    if (base + n1 < NN) *(ushort4*)&dst[(size_t)(base + n1) * 16 + col] = p1;
}

// ---------------- bucket histogram ----------------
__global__ __launch_bounds__(256) void hist_kernel(const void* ei, const int* flag,
                                                   int* bucketCnt) {
    __shared__ int h[NB];
    int t = threadIdx.x;
    for (int b = t; b < NB; b += 256) h[b] = 0;
    __syncthreads();
    int i64f = *flag;
    long long ebase = (long long)blockIdx.x * EB;
    for (int i = t; i < EB; i += 256) {
        long long e = ebase + i;
        if (e < NE) {
            int d = edge_at(ei, i64f, NE + e);
            atomicAdd(&h[d >> 7], 1);
        }
    }
    __syncthreads();
    for (int b = t; b < NB; b += 256) if (h[b]) atomicAdd(&bucketCnt[b], h[b]);
}

// ---------------- bucket scan (one block) ----------------
__global__ __launch_bounds__(1024) void scanb_kernel(const int* __restrict__ bucketCnt,
                                                     int* __restrict__ bucketBase,
                                                     int* __restrict__ gcursor,
                                                     int* __restrict__ rowptr) {
    __shared__ int sh[1024];
    int t = threadIdx.x;
    int v = (t < NB) ? bucketCnt[t] : 0;
    sh[t] = v;
    __syncthreads();
    for (int off = 1; off < 1024; off <<= 1) {
        int a = (t >= off) ? sh[t - off] : 0;
        __syncthreads();
        sh[t] += a;
        __syncthreads();
    }
    if (t < NB) {
        int excl = sh[t] - v;
        bucketBase[t] = excl;
        gcursor[t] = excl;
    }
    if (t == 0) { bucketBase[NB] = NE; rowptr[NN] = NE; }
}

// ---------------- bin edges into bucket regions ----------------
// packed word: (src << 7) | (dst & 127)
__global__ __launch_bounds__(256) void binscatter_kernel(const void* ei, const int* flag,
                                                         int* gcursor,
                                                         unsigned int* __restrict__ binned) {
    __shared__ int raws[EB];
    __shared__ int rawd[EB];
    __shared__ int h[NB];
    __shared__ int lcur[NB];
    int t = threadIdx.x;
    for (int b = t; b < NB; b += 256) h[b] = 0;
    __syncthreads();
    int i64f = *flag;
    long long ebase = (long long)blockIdx.x * EB;
    for (int i = t; i < EB; i += 256) {
        long long e = ebase + i;
        int s = 0, d = -1;
        if (e < NE) {
            s = edge_at(ei, i64f, e);
            d = edge_at(ei, i64f, NE + e);
            atomicAdd(&h[d >> 7], 1);
        }
        raws[i] = s;
        rawd[i] = d;
    }
    __syncthreads();
    for (int b = t; b < NB; b += 256) {
        lcur[b] = h[b] ? atomicAdd(&gcursor[b], h[b]) : 0;
    }
    __syncthreads();
    for (int i = t; i < EB; i += 256) {
        int d = rawd[i];
        if (d >= 0) {
            int b = d >> 7;
            int pos = atomicAdd(&lcur[b], 1);
            binned[pos] = ((unsigned)raws[i] << 7) | (unsigned)(d & 127);
        }
    }
}

// ---------------- per-bucket CSR ----------------
__global__ __launch_bounds__(256) void bucket_csr_kernel(const unsigned int* __restrict__ binned,
                                                         const int* __restrict__ bucketBase,
                                                         int* __restrict__ rowptr,
                                                         int* __restrict__ esrc) {
    __shared__ int cnt[128];
    __shared__ int sc[128];
    __shared__ int cur[128];
    int t = threadIdx.x;
    int b = blockIdx.x;
    int ebeg = bucketBase[b], eend = bucketBase[b + 1];
    if (t < 128) cnt[t] = 0;
    __syncthreads();
    for (int p = ebeg + t; p < eend; p += 256)
        atomicAdd(&cnt[binned[p] & 127], 1);
    __syncthreads();
    if (t < 128) sc[t] = cnt[t];
    __syncthreads();
    for (int off = 1; off < 128; off <<= 1) {
        int a = 0;
        if (t < 128 && t >= off) a = sc[t - off];
        __syncthreads();
        if (t < 128) sc[t] += a;
        __syncthreads();
    }
    if (t < 128) {
        int excl = sc[t] - cnt[t];
        int gn = (b << 7) + t;
        if (gn < NN) rowptr[gn] = ebeg + excl;
        cur[t] = excl;
    }
    __syncthreads();
    for (int p = ebeg + t; p < eend; p += 256) {
        unsigned w = binned[p];
        int dl = w & 127;
        int pos = ebeg + atomicAdd(&cur[dl], 1);
        esrc[pos] = w >> 7;
    }
}

// ---------------- agg16: gather-sum 16 bf16 features (L2-resident working set) ----------------
// one wave per node; 4 groups of 16 lanes split edges; writes fp32 agg[n][32] col block
__global__ __launch_bounds__(256) void agg16_kernel(const ushort_t* __restrict__ ysub,
                                                    const int* __restrict__ rowptr,
                                                    const int* __restrict__ esrc,
                                                    float* __restrict__ agg,
                                                    int colOff) {
    int t = threadIdx.x;
    int wv = t >> 6;
    int lane = t & 63;
    int grp = lane >> 4;      // 0..3
    int f = lane & 15;
    int n = blockIdx.x * 4 + wv;       // NN divisible by 4

    int beg = rowptr[n], end = rowptr[n + 1];
    float v0 = 0.f, v1 = 0.f;
    int p = beg + grp;
    for (; p + 4 < end; p += 8) {
        int s0 = esrc[p];
        int s1 = esrc[p + 4];
        float g0 = bf2f(ysub[(size_t)s0 * 16 + f]);
        float g1 = bf2f(ysub[(size_t)s1 * 16 + f]);
        v0 += g0; v1 += g1;
    }
    if (p < end) v0 += bf2f(ysub[(size_t)esrc[p] * 16 + f]);
    float v = v0 + v1;
    v += __shfl_xor(v, 16, 64);
    v += __shfl_xor(v, 32, 64);
    if (lane < 16) {
        v += bf2f(ysub[(size_t)n * 16 + f]);      // self (eps=0)
        agg[(size_t)n * 32 + colOff + f] = v;
    }
}

// ---------------- mlp1: y2 = relu(agg + b1a) @ Wc + bc1 -> bf16 split ----------------
__global__ __launch_bounds__(256) void mlp1_kernel(const float* __restrict__ agg,
                                                   const float* __restrict__ b1a,
                                                   const float* __restrict__ Wc,
                                                   const float* __restrict__ bc1,
                                                   ushort_t* __restrict__ y2lo,
                                                   ushort_t* __restrict__ y2hi) {
    __shared__ float Wl[HID * HID];
    __shared__ float b1l[HID];
    __shared__ float bcl[HID];
    int t = threadIdx.x;
    #pragma unroll
    for (int i = 0; i < 4; i++) Wl[i * 256 + t] = Wc[i * 256 + t];
    if (t < HID) { b1l[t] = b1a[t]; bcl[t] = bc1[t]; }
    __syncthreads();

    int sub = t >> 5;         // 0..7
    int f = t & 31;
    int n = blockIdx.x * 8 + sub;      // NN divisible by 8

    float u = agg[(size_t)n * 32 + f] + b1l[f];
    u = u > 0.f ? u : 0.f;
    float o = bcl[f];
    #pragma unroll
    for (int k = 0; k < HID; k++)
        o += __shfl(u, k, 32) * Wl[k * HID + f];

    ushort_t ob = f2bf(o);
    if (f < 16) y2lo[(size_t)n * 16 + f] = ob;
    else        y2hi[(size_t)n * 16 + (f - 16)] = ob;
}

// ---------------- mlp2: s = relu(agg + b2a) . wc2 + c0 ----------------
__global__ __launch_bounds__(256) void mlp2_kernel(const float* __restrict__ agg,
                                                   const float* __restrict__ b2a,
                                                   const float* __restrict__ wc2,
                                                   const float* __restrict__ c0,
                                                   float* __restrict__ sbuf) {
    __shared__ float wcl[HID];
    __shared__ float b2l[HID];
    int t = threadIdx.x;
    if (t < HID) { wcl[t] = wc2[t]; b2l[t] = b2a[t]; }
    __syncthreads();

    int sub = t >> 5;
    int f = t & 31;
    int n = blockIdx.x * 8 + sub;

    float u = agg[(size_t)n * 32 + f] + b2l[f];
    u = u > 0.f ? u : 0.f;
    float tt = u * wcl[f];
    #pragma unroll
    for (int off = 16; off > 0; off >>= 1) tt += __shfl_xor(tt, off, 32);
    if (f == 0) sbuf[n] = tt + *c0;
}

// ---------------- layer3: scalar aggregate (sbuf is L2-resident) ----------------
__global__ __launch_bounds__(256) void final_kernel(const float* __restrict__ sbuf,
                                                    const int* __restrict__ rowptr,
                                                    const int* __restrict__ esrc,
                                                    const float* __restrict__ b3,
                                                    float* __restrict__ out) {
    int n = blockIdx.x * 256 + threadIdx.x;
    if (n >= NN) return;
    float v = sbuf[n] + b3[0];
    int beg = rowptr[n], end = rowptr[n + 1];
    int p = beg;
    for (; p + 4 <= end; p += 4) {
        int s0 = esrc[p], s1 = esrc[p + 1], s2 = esrc[p + 2], s3 = esrc[p + 3];
        float g0 = sbuf[s0], g1 = sbuf[s1], g2 = sbuf[s2], g3 = sbuf[s3];
        v += g0; v += g1; v += g2; v += g3;
    }
    for (; p < end; p++) v += sbuf[esrc[p]];
    out[n] = v;
}

// ---------------- host ----------------
extern "C" void kernel_launch(void* const* d_in, const int* in_sizes, int n_in,
                              void* d_out, int out_size, void* d_ws, size_t ws_size,
                              hipStream_t stream) {
    const float* x   = (const float*)d_in[0];
    const void*  ei  = d_in[1];
    const float* w1a = (const float*)d_in[2];
    const float* b1a = (const float*)d_in[3];
    const float* w1b = (const float*)d_in[4];
    const float* b1b = (const float*)d_in[5];
    const float* w2a = (const float*)d_in[6];
    const float* b2a = (const float*)d_in[7];
    const float* w2b = (const float*)d_in[8];
    const float* b2b = (const float*)d_in[9];
    const float* w3  = (const float*)d_in[10];
    const float* b3  = (const float*)d_in[11];
    float* out = (float*)d_out;

    char* w = (char*)d_ws;
    ushort_t*     y1lo       = (ushort_t*)(w + 0);           //  3,200,000
    ushort_t*     y1hi       = (ushort_t*)(w + 3200000);     //  3,200,000
    ushort_t*     y2lo       = (ushort_t*)(w + 6400000);     //  3,200,000
    ushort_t*     y2hi       = (ushort_t*)(w + 9600000);     //  3,200,000
    int*          esrc       = (int*)     (w + 12800000);    //  6,400,000
    int*          rowptr     = (int*)     (w + 19200000);    //    400,016
    float*        sbuf       = (float*)   (w + 19600016);    //    400,000
    int*          bucketCnt  = (int*)     (w + 20000016);    //      3,136
    int*          bucketBase = (int*)     (w + 20003152);    //      3,136
    int*          gcursor    = (int*)     (w + 20006288);    //      3,136
    int*          flag       = (int*)     (w + 20009424);    //         16
    float*        Wc         = (float*)   (w + 20009440);    //      4,096
    float*        bc1        = (float*)   (w + 20013536);    //        128
    float*        wc2        = (float*)   (w + 20013664);    //        128
    float*        c0         = (float*)   (w + 20013792);    //         32
    // binned (6.4 MB) overlays agg (12.8 MB fp32) — binned dead after bucket_csr
    unsigned int* binned     = (unsigned int*)(w + 20013824);
    float*        agg        = (float*)      (w + 20013824); // ends at 32,813,824

    detect_kernel<<<1, 1, 0, stream>>>(ei, flag);
    zero_kernel<<<1, 1024, 0, stream>>>(bucketCnt);
    precompute_kernel<<<1, 1024, 0, stream>>>(w1b, b1b, w2a, w2b, b2b, w3, Wc, bc1, wc2, c0);
    proj1_kernel<<<(NN + 63) / 64, 256, 0, stream>>>(x, w1a, y1lo, y1hi);

    hist_kernel<<<NBA, 256, 0, stream>>>(ei, flag, bucketCnt);
    scanb_kernel<<<1, 1024, 0, stream>>>(bucketCnt, bucketBase, gcursor, rowptr);
    binscatter_kernel<<<NBA, 256, 0, stream>>>(ei, flag, gcursor, binned);
    bucket_csr_kernel<<<NB, 256, 0, stream>>>(binned, bucketBase, rowptr, esrc);

    // layer 1: two L2-resident gather passes + streaming MLP
    agg16_kernel<<<NN / 4, 256, 0, stream>>>(y1lo, rowptr, esrc, agg, 0);
    agg16_kernel<<<NN / 4, 256, 0, stream>>>(y1hi, rowptr, esrc, agg, 16);
    mlp1_kernel<<<NN / 8, 256, 0, stream>>>(agg, b1a, Wc, bc1, y2lo, y2hi);

    // layer 2
    agg16_kernel<<<NN / 4, 256, 0, stream>>>(y2lo, rowptr, esrc, agg, 0);
    agg16_kernel<<<NN / 4, 256, 0, stream>>>(y2hi, rowptr, esrc, agg, 16);
    mlp2_kernel<<<NN / 8, 256, 0, stream>>>(agg, b2a, wc2, c0, sbuf);

    // layer 3
    final_kernel<<<(NN + 255) / 256, 256, 0, stream>>>(sbuf, rowptr, esrc, b3, out);
}

// Round 5
// 213.729 us; speedup vs baseline: 1.4412x; 1.4412x over previous
//
#include <hip/hip_runtime.h>

#define NN 100000
#define NE 1600000
#define IC 128
#define HID 32
#define NB 782          // buckets of 128 nodes
#define EB 4096         // edges per binning block
#define NBA 391         // ceil(NE/EB)

typedef unsigned short ushort_t;

__device__ __forceinline__ ushort_t f2bf(float x) {
    unsigned u = __float_as_uint(x);
    unsigned r = (u + 0x7fffu + ((u >> 16) & 1u)) >> 16;   // round-to-nearest-even
    return (ushort_t)r;
}
__device__ __forceinline__ float bf2f(ushort_t b) {
    return __uint_as_float(((unsigned)b) << 16);
}

// ---------------- edge dtype detection ----------------
__global__ void detect_kernel(const void* ei, int* flag) {
    const long long* p = (const long long*)ei;
    int ok = 1;
    for (int i = 0; i < 64; i++) {
        long long v = p[i];
        if (v < 0 || v >= NN) ok = 0;
    }
    *flag = ok;
}

__device__ __forceinline__ int edge_at(const void* ei, int i64f, long long idx) {
    return i64f ? (int)((const long long*)ei)[idx] : ((const int*)ei)[idx];
}

__global__ void zero_kernel(int* bucketCnt) {
    int t = threadIdx.x;
    if (t < NB) bucketCnt[t] = 0;
}

// Fold w1b@w2a, b1b@w2a, w2b@w3, b2b@w3.
__global__ void precompute_kernel(const float* __restrict__ w1b, const float* __restrict__ b1b,
                                  const float* __restrict__ w2a, const float* __restrict__ w2b,
                                  const float* __restrict__ b2b, const float* __restrict__ w3,
                                  float* Wc, float* bc1, float* wc2, float* c0) {
    int t = threadIdx.x;           // 1024 threads
    int k = t >> 5, j = t & 31;
    float acc = 0.f;
    for (int m = 0; m < HID; m++) acc += w1b[k * HID + m] * w2a[m * HID + j];
    Wc[k * HID + j] = acc;
    if (t < 32) {
        float a = 0.f;
        for (int m = 0; m < HID; m++) a += b1b[m] * w2a[m * HID + t];
        bc1[t] = a;
    } else if (t < 64) {
        int kk = t - 32;
        float a = 0.f;
        for (int jj = 0; jj < HID; jj++) a += w2b[kk * HID + jj] * w3[jj];
        wc2[kk] = a;
    } else if (t == 64) {
        float a = 0.f;
        for (int jj = 0; jj < HID; jj++) a += b2b[jj] * w3[jj];
        *c0 = a;
    }
}

// ---------------- proj1: y1 = x @ w1a, output bf16[n][32] (one 64B line/row) ----------------
__global__ __launch_bounds__(256) void proj1_kernel(const float* __restrict__ x,
                                                    const float* __restrict__ w1a,
                                                    ushort_t* __restrict__ y1) {
    __shared__ float xs[64 * 132];
    __shared__ float ws[IC * HID];
    int t = threadIdx.x;
    int base = blockIdx.x * 64;

    #pragma unroll
    for (int i = 0; i < 16; i++) ws[i * 256 + t] = w1a[i * 256 + t];

    const float4* xg = (const float4*)x;
    #pragma unroll
    for (int i = 0; i < 8; i++) {
        int fi = i * 256 + t;
        int row = fi >> 5;
        int kq = fi & 31;
        float4 v = make_float4(0.f, 0.f, 0.f, 0.f);
        if (base + row < NN) v = xg[(size_t)(base + row) * 32 + kq];
        *(float4*)&xs[row * 132 + kq * 4] = v;
    }
    __syncthreads();

    int ng = t >> 3;
    int fg = t & 7;
    int n0 = ng * 2, n1 = n0 + 1;
    int j0 = fg * 4;
    float4 a0 = make_float4(0.f, 0.f, 0.f, 0.f);
    float4 a1 = make_float4(0.f, 0.f, 0.f, 0.f);
    #pragma unroll 8
    for (int k = 0; k < IC; k++) {
        float x0 = xs[n0 * 132 + k];
        float x1 = xs[n1 * 132 + k];
        float4 w = *(const float4*)&ws[k * HID + j0];
        a0.x += x0 * w.x; a0.y += x0 * w.y; a0.z += x0 * w.z; a0.w += x0 * w.w;
        a1.x += x1 * w.x; a1.y += x1 * w.y; a1.z += x1 * w.z; a1.w += x1 * w.w;
    }
    ushort4 p0, p1;
    p0.x = f2bf(a0.x); p0.y = f2bf(a0.y); p0.z = f2bf(a0.z); p0.w = f2bf(a0.w);
    p1.x = f2bf(a1.x); p1.y = f2bf(a1.y); p1.z = f2bf(a1.z); p1.w = f2bf(a1.w);
    if (base + n0 < NN) *(ushort4*)&y1[(size_t)(base + n0) * 32 + j0] = p0;
    if (base + n1 < NN) *(ushort4*)&y1[(size_t)(base + n1) * 32 + j0] = p1;
}

// ---------------- bucket histogram ----------------
__global__ __launch_bounds__(256) void hist_kernel(const void* ei, const int* flag,
                                                   int* bucketCnt) {
    __shared__ int h[NB];
    int t = threadIdx.x;
    for (int b = t; b < NB; b += 256) h[b] = 0;
    __syncthreads();
    int i64f = *flag;
    long long ebase = (long long)blockIdx.x * EB;
    for (int i = t; i < EB; i += 256) {
        long long e = ebase + i;
        if (e < NE) {
            int d = edge_at(ei, i64f, NE + e);
            atomicAdd(&h[d >> 7], 1);
        }
    }
    __syncthreads();
    for (int b = t; b < NB; b += 256) if (h[b]) atomicAdd(&bucketCnt[b], h[b]);
}

// ---------------- bucket scan (one block) ----------------
__global__ __launch_bounds__(1024) void scanb_kernel(const int* __restrict__ bucketCnt,
                                                     int* __restrict__ bucketBase,
                                                     int* __restrict__ gcursor,
                                                     int* __restrict__ rowptr) {
    __shared__ int sh[1024];
    int t = threadIdx.x;
    int v = (t < NB) ? bucketCnt[t] : 0;
    sh[t] = v;
    __syncthreads();
    for (int off = 1; off < 1024; off <<= 1) {
        int a = (t >= off) ? sh[t - off] : 0;
        __syncthreads();
        sh[t] += a;
        __syncthreads();
    }
    if (t < NB) {
        int excl = sh[t] - v;
        bucketBase[t] = excl;
        gcursor[t] = excl;
    }
    if (t == 0) { bucketBase[NB] = NE; rowptr[NN] = NE; }
}

// ---------------- bin edges into bucket regions ----------------
// packed word: (src << 7) | (dst & 127)
__global__ __launch_bounds__(256) void binscatter_kernel(const void* ei, const int* flag,
                                                         int* gcursor,
                                                         unsigned int* __restrict__ binned) {
    __shared__ int raws[EB];
    __shared__ int rawd[EB];
    __shared__ int h[NB];
    __shared__ int lcur[NB];
    int t = threadIdx.x;
    for (int b = t; b < NB; b += 256) h[b] = 0;
    __syncthreads();
    int i64f = *flag;
    long long ebase = (long long)blockIdx.x * EB;
    for (int i = t; i < EB; i += 256) {
        long long e = ebase + i;
        int s = 0, d = -1;
        if (e < NE) {
            s = edge_at(ei, i64f, e);
            d = edge_at(ei, i64f, NE + e);
            atomicAdd(&h[d >> 7], 1);
        }
        raws[i] = s;
        rawd[i] = d;
    }
    __syncthreads();
    for (int b = t; b < NB; b += 256) {
        lcur[b] = h[b] ? atomicAdd(&gcursor[b], h[b]) : 0;
    }
    __syncthreads();
    for (int i = t; i < EB; i += 256) {
        int d = rawd[i];
        if (d >= 0) {
            int b = d >> 7;
            int pos = atomicAdd(&lcur[b], 1);
            binned[pos] = ((unsigned)raws[i] << 7) | (unsigned)(d & 127);
        }
    }
}

// ---------------- per-bucket CSR ----------------
__global__ __launch_bounds__(256) void bucket_csr_kernel(const unsigned int* __restrict__ binned,
                                                         const int* __restrict__ bucketBase,
                                                         int* __restrict__ rowptr,
                                                         int* __restrict__ esrc) {
    __shared__ int cnt[128];
    __shared__ int sc[128];
    __shared__ int cur[128];
    int t = threadIdx.x;
    int b = blockIdx.x;
    int ebeg = bucketBase[b], eend = bucketBase[b + 1];
    if (t < 128) cnt[t] = 0;
    __syncthreads();
    for (int p = ebeg + t; p < eend; p += 256)
        atomicAdd(&cnt[binned[p] & 127], 1);
    __syncthreads();
    if (t < 128) sc[t] = cnt[t];
    __syncthreads();
    for (int off = 1; off < 128; off <<= 1) {
        int a = 0;
        if (t < 128 && t >= off) a = sc[t - off];
        __syncthreads();
        if (t < 128) sc[t] += a;
        __syncthreads();
    }
    if (t < 128) {
        int excl = sc[t] - cnt[t];
        int gn = (b << 7) + t;
        if (gn < NN) rowptr[gn] = ebeg + excl;
        cur[t] = excl;
    }
    __syncthreads();
    for (int p = ebeg + t; p < eend; p += 256) {
        unsigned w = binned[p];
        int dl = w & 127;
        int pos = ebeg + atomicAdd(&cur[dl], 1);
        esrc[pos] = w >> 7;
    }
}

// ---------------- agg32: one-pass gather-sum of bf16[n][32] rows ----------------
// one wave per node; 8 groups of 8 lanes; each group 1 edge/iter, lane loads ushort4 (8B)
// => 8 edges per wave-instruction, exactly 1 cache line per edge.
__global__ __launch_bounds__(256) void agg32_kernel(const ushort_t* __restrict__ y,
                                                    const int* __restrict__ rowptr,
                                                    const int* __restrict__ esrc,
                                                    float* __restrict__ agg) {
    int t = threadIdx.x;
    int wv = t >> 6;
    int lane = t & 63;
    int grp = lane >> 3;      // 0..7
    int l = lane & 7;         // lane in group -> features 4l..4l+3
    int n = blockIdx.x * 4 + wv;       // NN divisible by 4

    int beg = rowptr[n], end = rowptr[n + 1];
    float ax0 = 0.f, ay0 = 0.f, az0 = 0.f, aw0 = 0.f;
    float ax1 = 0.f, ay1 = 0.f, az1 = 0.f, aw1 = 0.f;
    int p = beg + grp;
    for (; p + 8 < end; p += 16) {
        int s0 = esrc[p];
        int s1 = esrc[p + 8];
        ushort4 u0 = *(const ushort4*)&y[(size_t)s0 * 32 + l * 4];
        ushort4 u1 = *(const ushort4*)&y[(size_t)s1 * 32 + l * 4];
        ax0 += bf2f(u0.x); ay0 += bf2f(u0.y); az0 += bf2f(u0.z); aw0 += bf2f(u0.w);
        ax1 += bf2f(u1.x); ay1 += bf2f(u1.y); az1 += bf2f(u1.z); aw1 += bf2f(u1.w);
    }
    if (p < end) {
        ushort4 u0 = *(const ushort4*)&y[(size_t)esrc[p] * 32 + l * 4];
        ax0 += bf2f(u0.x); ay0 += bf2f(u0.y); az0 += bf2f(u0.z); aw0 += bf2f(u0.w);
    }
    float vx = ax0 + ax1, vy = ay0 + ay1, vz = az0 + az1, vw = aw0 + aw1;
    vx += __shfl_xor(vx, 8, 64);  vy += __shfl_xor(vy, 8, 64);
    vz += __shfl_xor(vz, 8, 64);  vw += __shfl_xor(vw, 8, 64);
    vx += __shfl_xor(vx, 16, 64); vy += __shfl_xor(vy, 16, 64);
    vz += __shfl_xor(vz, 16, 64); vw += __shfl_xor(vw, 16, 64);
    vx += __shfl_xor(vx, 32, 64); vy += __shfl_xor(vy, 32, 64);
    vz += __shfl_xor(vz, 32, 64); vw += __shfl_xor(vw, 32, 64);
    if (lane < 8) {
        ushort4 us = *(const ushort4*)&y[(size_t)n * 32 + l * 4];   // self (eps=0)
        float4 o;
        o.x = vx + bf2f(us.x);
        o.y = vy + bf2f(us.y);
        o.z = vz + bf2f(us.z);
        o.w = vw + bf2f(us.w);
        *(float4*)&agg[(size_t)n * 32 + l * 4] = o;
    }
}

// ---------------- mlp1: y2 = relu(agg + b1a) @ Wc + bc1 -> bf16[n][32] ----------------
__global__ __launch_bounds__(256) void mlp1_kernel(const float* __restrict__ agg,
                                                   const float* __restrict__ b1a,
                                                   const float* __restrict__ Wc,
                                                   const float* __restrict__ bc1,
                                                   ushort_t* __restrict__ y2) {
    __shared__ float Wl[HID * HID];
    __shared__ float b1l[HID];
    __shared__ float bcl[HID];
    int t = threadIdx.x;
    #pragma unroll
    for (int i = 0; i < 4; i++) Wl[i * 256 + t] = Wc[i * 256 + t];
    if (t < HID) { b1l[t] = b1a[t]; bcl[t] = bc1[t]; }
    __syncthreads();

    int sub = t >> 5;         // 0..7
    int f = t & 31;
    int n = blockIdx.x * 8 + sub;      // NN divisible by 8

    float u = agg[(size_t)n * 32 + f] + b1l[f];
    u = u > 0.f ? u : 0.f;
    float o = bcl[f];
    #pragma unroll
    for (int k = 0; k < HID; k++)
        o += __shfl(u, k, 32) * Wl[k * HID + f];

    y2[(size_t)n * 32 + f] = f2bf(o);
}

// ---------------- mlp2: s = relu(agg + b2a) . wc2 + c0 ----------------
__global__ __launch_bounds__(256) void mlp2_kernel(const float* __restrict__ agg,
                                                   const float* __restrict__ b2a,
                                                   const float* __restrict__ wc2,
                                                   const float* __restrict__ c0,
                                                   float* __restrict__ sbuf) {
    __shared__ float wcl[HID];
    __shared__ float b2l[HID];
    int t = threadIdx.x;
    if (t < HID) { wcl[t] = wc2[t]; b2l[t] = b2a[t]; }
    __syncthreads();

    int sub = t >> 5;
    int f = t & 31;
    int n = blockIdx.x * 8 + sub;

    float u = agg[(size_t)n * 32 + f] + b2l[f];
    u = u > 0.f ? u : 0.f;
    float tt = u * wcl[f];
    #pragma unroll
    for (int off = 16; off > 0; off >>= 1) tt += __shfl_xor(tt, off, 32);
    if (f == 0) sbuf[n] = tt + *c0;
}

// ---------------- layer3: scalar aggregate (sbuf is L2-resident) ----------------
__global__ __launch_bounds__(256) void final_kernel(const float* __restrict__ sbuf,
                                                    const int* __restrict__ rowptr,
                                                    const int* __restrict__ esrc,
                                                    const float* __restrict__ b3,
                                                    float* __restrict__ out) {
    int n = blockIdx.x * 256 + threadIdx.x;
    if (n >= NN) return;
    float v = sbuf[n] + b3[0];
    int beg = rowptr[n], end = rowptr[n + 1];
    int p = beg;
    for (; p + 4 <= end; p += 4) {
        int s0 = esrc[p], s1 = esrc[p + 1], s2 = esrc[p + 2], s3 = esrc[p + 3];
        float g0 = sbuf[s0], g1 = sbuf[s1], g2 = sbuf[s2], g3 = sbuf[s3];
        v += g0; v += g1; v += g2; v += g3;
    }
    for (; p < end; p++) v += sbuf[esrc[p]];
    out[n] = v;
}

// ---------------- host ----------------
extern "C" void kernel_launch(void* const* d_in, const int* in_sizes, int n_in,
                              void* d_out, int out_size, void* d_ws, size_t ws_size,
                              hipStream_t stream) {
    const float* x   = (const float*)d_in[0];
    const void*  ei  = d_in[1];
    const float* w1a = (const float*)d_in[2];
    const float* b1a = (const float*)d_in[3];
    const float* w1b = (const float*)d_in[4];
    const float* b1b = (const float*)d_in[5];
    const float* w2a = (const float*)d_in[6];
    const float* b2a = (const float*)d_in[7];
    const float* w2b = (const float*)d_in[8];
    const float* b2b = (const float*)d_in[9];
    const float* w3  = (const float*)d_in[10];
    const float* b3  = (const float*)d_in[11];
    float* out = (float*)d_out;

    char* w = (char*)d_ws;
    ushort_t*     y1         = (ushort_t*)(w + 0);           //  6,400,000
    ushort_t*     y2         = (ushort_t*)(w + 6400000);     //  6,400,000
    int*          esrc       = (int*)     (w + 12800000);    //  6,400,000
    int*          rowptr     = (int*)     (w + 19200000);    //    400,016
    float*        sbuf       = (float*)   (w + 19600016);    //    400,000
    int*          bucketCnt  = (int*)     (w + 20000016);    //      3,136
    int*          bucketBase = (int*)     (w + 20003152);    //      3,136
    int*          gcursor    = (int*)     (w + 20006288);    //      3,136
    int*          flag       = (int*)     (w + 20009424);    //         16
    float*        Wc         = (float*)   (w + 20009440);    //      4,096
    float*        bc1        = (float*)   (w + 20013536);    //        128
    float*        wc2        = (float*)   (w + 20013664);    //        128
    float*        c0         = (float*)   (w + 20013792);    //         32
    // binned (6.4 MB) overlays agg (12.8 MB fp32) — binned dead after bucket_csr
    unsigned int* binned     = (unsigned int*)(w + 20013824);
    float*        agg        = (float*)      (w + 20013824); // ends at 32,813,824

    detect_kernel<<<1, 1, 0, stream>>>(ei, flag);
    zero_kernel<<<1, 1024, 0, stream>>>(bucketCnt);
    precompute_kernel<<<1, 1024, 0, stream>>>(w1b, b1b, w2a, w2b, b2b, w3, Wc, bc1, wc2, c0);
    proj1_kernel<<<(NN + 63) / 64, 256, 0, stream>>>(x, w1a, y1);

    hist_kernel<<<NBA, 256, 0, stream>>>(ei, flag, bucketCnt);
    scanb_kernel<<<1, 1024, 0, stream>>>(bucketCnt, bucketBase, gcursor, rowptr);
    binscatter_kernel<<<NBA, 256, 0, stream>>>(ei, flag, gcursor, binned);
    bucket_csr_kernel<<<NB, 256, 0, stream>>>(binned, bucketBase, rowptr, esrc);

    // layer 1: single-pass line-optimal gather + streaming MLP
    agg32_kernel<<<NN / 4, 256, 0, stream>>>(y1, rowptr, esrc, agg);
    mlp1_kernel<<<NN / 8, 256, 0, stream>>>(agg, b1a, Wc, bc1, y2);

    // layer 2
    agg32_kernel<<<NN / 4, 256, 0, stream>>>(y2, rowptr, esrc, agg);
    mlp2_kernel<<<NN / 8, 256, 0, stream>>>(agg, b2a, wc2, c0, sbuf);

    // layer 3
    final_kernel<<<(NN + 255) / 256, 256, 0, stream>>>(sbuf, rowptr, esrc, b3, out);
}

// Round 6
// 188.641 us; speedup vs baseline: 1.6328x; 1.1330x over previous
//
#include <hip/hip_runtime.h>

#define NN 100000
#define NE 1600000
#define IC 128
#define HID 32
#define NB 782           // buckets of 128 nodes
#define BCAP 2560        // padded bucket capacity (mean 2048, sigma~45 -> +11 sigma)
#define EB 4096          // edges per binning block
#define NBA 391          // ceil(NE/EB)
#define NPJ 1563         // ceil(NN/64) proj blocks

typedef unsigned short ushort_t;

__device__ __forceinline__ ushort_t f2bf(float x) {
    unsigned u = __float_as_uint(x);
    unsigned r = (u + 0x7fffu + ((u >> 16) & 1u)) >> 16;   // RNE
    return (ushort_t)r;
}
__device__ __forceinline__ float bf2f(ushort_t b) {
    return __uint_as_float(((unsigned)b) << 16);
}

__device__ __forceinline__ int edge_at(const void* ei, int i64f, long long idx) {
    return i64f ? (int)((const long long*)ei)[idx] : ((const int*)ei)[idx];
}

// ---------------- setup: detect dtype + precompute folded weights + zero cursors ----------------
__global__ __launch_bounds__(1024) void setup_kernel(const void* ei,
                                                     const float* __restrict__ w1b, const float* __restrict__ b1b,
                                                     const float* __restrict__ w2a, const float* __restrict__ w2b,
                                                     const float* __restrict__ b2b, const float* __restrict__ w3,
                                                     int* flag, int* gcursor,
                                                     float* Wc, float* bc1, float* wc2, float* c0) {
    int t = threadIdx.x;
    if (blockIdx.x == 1) {
        if (t < NB) gcursor[t] = 0;
        return;
    }
    // block 0: detect (wave 0) + precompute (all threads)
    if (t < 64) {
        const long long* p = (const long long*)ei;
        long long v = p[t];
        unsigned long long bad = __ballot(v < 0 || v >= NN);
        if (t == 0) *flag = (bad == 0ull) ? 1 : 0;
    }
    int k = t >> 5, j = t & 31;
    float acc = 0.f;
    for (int m = 0; m < HID; m++) acc += w1b[k * HID + m] * w2a[m * HID + j];
    Wc[k * HID + j] = acc;
    if (t < 32) {
        float a = 0.f;
        for (int m = 0; m < HID; m++) a += b1b[m] * w2a[m * HID + t];
        bc1[t] = a;
    } else if (t < 64) {
        int kk = t - 32;
        float a = 0.f;
        for (int jj = 0; jj < HID; jj++) a += w2b[kk * HID + jj] * w3[jj];
        wc2[kk] = a;
    } else if (t == 64) {
        float a = 0.f;
        for (int jj = 0; jj < HID; jj++) a += b2b[jj] * w3[jj];
        *c0 = a;
    }
}

// ---------------- proj1 + binscatter merged (independent work, concurrent blocks) ----------------
union SMU {
    struct { float xs[64 * 132]; float ws[IC * HID]; } pj;          // 50,176 B
    struct { int raws[EB]; int rawd[EB]; int h[NB]; int lcur[NB]; } bs; // 39,024 B
};

__global__ __launch_bounds__(256) void proj_bin_kernel(const float* __restrict__ x,
                                                       const float* __restrict__ w1a,
                                                       ushort_t* __restrict__ y1,
                                                       const void* ei, const int* flag,
                                                       int* gcursor,
                                                       unsigned int* __restrict__ binned) {
    __shared__ SMU sm;
    int t = threadIdx.x;

    if (blockIdx.x < NPJ) {
        // ---- proj1: y1 = bf16(x @ w1a), one 64B line per node row ----
        int base = blockIdx.x * 64;
        #pragma unroll
        for (int i = 0; i < 16; i++) sm.pj.ws[i * 256 + t] = w1a[i * 256 + t];
        const float4* xg = (const float4*)x;
        #pragma unroll
        for (int i = 0; i < 8; i++) {
            int fi = i * 256 + t;
            int row = fi >> 5;
            int kq = fi & 31;
            float4 v = make_float4(0.f, 0.f, 0.f, 0.f);
            if (base + row < NN) v = xg[(size_t)(base + row) * 32 + kq];
            *(float4*)&sm.pj.xs[row * 132 + kq * 4] = v;
        }
        __syncthreads();

        int ng = t >> 3;
        int fg = t & 7;
        int n0 = ng * 2, n1 = n0 + 1;
        int j0 = fg * 4;
        float4 a0 = make_float4(0.f, 0.f, 0.f, 0.f);
        float4 a1 = make_float4(0.f, 0.f, 0.f, 0.f);
        #pragma unroll 8
        for (int k = 0; k < IC; k++) {
            float x0 = sm.pj.xs[n0 * 132 + k];
            float x1 = sm.pj.xs[n1 * 132 + k];
            float4 w = *(const float4*)&sm.pj.ws[k * HID + j0];
            a0.x += x0 * w.x; a0.y += x0 * w.y; a0.z += x0 * w.z; a0.w += x0 * w.w;
            a1.x += x1 * w.x; a1.y += x1 * w.y; a1.z += x1 * w.z; a1.w += x1 * w.w;
        }
        ushort4 p0, p1;
        p0.x = f2bf(a0.x); p0.y = f2bf(a0.y); p0.z = f2bf(a0.z); p0.w = f2bf(a0.w);
        p1.x = f2bf(a1.x); p1.y = f2bf(a1.y); p1.z = f2bf(a1.z); p1.w = f2bf(a1.w);
        if (base + n0 < NN) *(ushort4*)&y1[(size_t)(base + n0) * 32 + j0] = p0;
        if (base + n1 < NN) *(ushort4*)&y1[(size_t)(base + n1) * 32 + j0] = p1;
    } else {
        // ---- binscatter: bin edges into padded bucket regions ----
        int bb = blockIdx.x - NPJ;
        for (int b = t; b < NB; b += 256) sm.bs.h[b] = 0;
        __syncthreads();
        int i64f = *flag;
        long long ebase = (long long)bb * EB;
        for (int i = t; i < EB; i += 256) {
            long long e = ebase + i;
            int s = 0, d = -1;
            if (e < NE) {
                s = edge_at(ei, i64f, e);
                d = edge_at(ei, i64f, NE + e);
                atomicAdd(&sm.bs.h[d >> 7], 1);
            }
            sm.bs.raws[i] = s;
            sm.bs.rawd[i] = d;
        }
        __syncthreads();
        for (int b = t; b < NB; b += 256)
            sm.bs.lcur[b] = sm.bs.h[b] ? atomicAdd(&gcursor[b], sm.bs.h[b]) : 0;
        __syncthreads();
        for (int i = t; i < EB; i += 256) {
            int d = sm.bs.rawd[i];
            if (d >= 0) {
                int b = d >> 7;
                int pos = atomicAdd(&sm.bs.lcur[b], 1);
                binned[(size_t)b * BCAP + pos] = ((unsigned)sm.bs.raws[i] << 7) | (unsigned)(d & 127);
            }
        }
    }
}

// ---------------- per-bucket CSR into padded esrc ----------------
__global__ __launch_bounds__(256) void bucket_csr_kernel(const unsigned int* __restrict__ binned,
                                                         const int* __restrict__ gcursor,
                                                         int* __restrict__ rowbeg,
                                                         int* __restrict__ rowend,
                                                         int* __restrict__ esrc) {
    __shared__ int cnt[128];
    __shared__ int sc[128];
    __shared__ int cur[128];
    int t = threadIdx.x;
    int b = blockIdx.x;
    int n = gcursor[b];
    int bbase = b * BCAP;
    if (t < 128) cnt[t] = 0;
    __syncthreads();
    for (int p = t; p < n; p += 256)
        atomicAdd(&cnt[binned[bbase + p] & 127], 1);
    __syncthreads();
    if (t < 128) sc[t] = cnt[t];
    __syncthreads();
    for (int off = 1; off < 128; off <<= 1) {
        int a = 0;
        if (t < 128 && t >= off) a = sc[t - off];
        __syncthreads();
        if (t < 128) sc[t] += a;
        __syncthreads();
    }
    if (t < 128) {
        int excl = sc[t] - cnt[t];
        int gn = (b << 7) + t;
        if (gn < NN) { rowbeg[gn] = bbase + excl; rowend[gn] = bbase + excl + cnt[t]; }
        cur[t] = excl;
    }
    __syncthreads();
    for (int p = t; p < n; p += 256) {
        unsigned w = binned[bbase + p];
        int dl = w & 127;
        int pos = bbase + atomicAdd(&cur[dl], 1);
        esrc[pos] = w >> 7;
    }
}

// ---------------- layer1 fused: agg + relu + matvec -> y2 bf16 ----------------
__global__ __launch_bounds__(256) void agg_mlp1_kernel(const ushort_t* __restrict__ y1,
                                                       const int* __restrict__ rowbeg,
                                                       const int* __restrict__ rowend,
                                                       const int* __restrict__ esrc,
                                                       const float* __restrict__ b1a,
                                                       const float* __restrict__ Wc,
                                                       const float* __restrict__ bc1,
                                                       ushort_t* __restrict__ y2) {
    __shared__ float Wl[HID * HID];
    __shared__ float b1l[HID];
    __shared__ float bcl[HID];
    int t = threadIdx.x;
    #pragma unroll
    for (int i = 0; i < 4; i++) Wl[i * 256 + t] = Wc[i * 256 + t];
    if (t < HID) { b1l[t] = b1a[t]; bcl[t] = bc1[t]; }
    __syncthreads();

    int wv = t >> 6;
    int lane = t & 63;
    int grp = lane >> 3;
    int l = lane & 7;
    int n = blockIdx.x * 4 + wv;       // NN divisible by 4

    int beg = rowbeg[n], end = rowend[n];
    float ax0 = 0.f, ay0 = 0.f, az0 = 0.f, aw0 = 0.f;
    float ax1 = 0.f, ay1 = 0.f, az1 = 0.f, aw1 = 0.f;
    int p = beg + grp;
    for (; p + 8 < end; p += 16) {
        int s0 = esrc[p];
        int s1 = esrc[p + 8];
        ushort4 u0 = *(const ushort4*)&y1[(size_t)s0 * 32 + l * 4];
        ushort4 u1 = *(const ushort4*)&y1[(size_t)s1 * 32 + l * 4];
        ax0 += bf2f(u0.x); ay0 += bf2f(u0.y); az0 += bf2f(u0.z); aw0 += bf2f(u0.w);
        ax1 += bf2f(u1.x); ay1 += bf2f(u1.y); az1 += bf2f(u1.z); aw1 += bf2f(u1.w);
    }
    if (p < end) {
        ushort4 u0 = *(const ushort4*)&y1[(size_t)esrc[p] * 32 + l * 4];
        ax0 += bf2f(u0.x); ay0 += bf2f(u0.y); az0 += bf2f(u0.z); aw0 += bf2f(u0.w);
    }
    float vx = ax0 + ax1, vy = ay0 + ay1, vz = az0 + az1, vw = aw0 + aw1;
    vx += __shfl_xor(vx, 8, 64);  vy += __shfl_xor(vy, 8, 64);
    vz += __shfl_xor(vz, 8, 64);  vw += __shfl_xor(vw, 8, 64);
    vx += __shfl_xor(vx, 16, 64); vy += __shfl_xor(vy, 16, 64);
    vz += __shfl_xor(vz, 16, 64); vw += __shfl_xor(vw, 16, 64);
    vx += __shfl_xor(vx, 32, 64); vy += __shfl_xor(vy, 32, 64);
    vz += __shfl_xor(vz, 32, 64); vw += __shfl_xor(vw, 32, 64);

    // self (eps=0) + bias + relu ; every lane holds features 4l..4l+3 replicated
    ushort4 us = *(const ushort4*)&y1[(size_t)n * 32 + l * 4];
    float ux = vx + bf2f(us.x) + b1l[l * 4 + 0];
    float uy = vy + bf2f(us.y) + b1l[l * 4 + 1];
    float uz = vz + bf2f(us.z) + b1l[l * 4 + 2];
    float uw = vw + bf2f(us.w) + b1l[l * 4 + 3];
    ux = ux > 0.f ? ux : 0.f;
    uy = uy > 0.f ? uy : 0.f;
    uz = uz > 0.f ? uz : 0.f;
    uw = uw > 0.f ? uw : 0.f;

    // matvec: o[f] = bc1[f] + sum_k u[k] * Wc[k][f]
    int f = lane & 31;
    float o = bcl[f];
    #pragma unroll
    for (int q = 0; q < 8; q++) {
        float c0v = __shfl(ux, q, 64);
        float c1v = __shfl(uy, q, 64);
        float c2v = __shfl(uz, q, 64);
        float c3v = __shfl(uw, q, 64);
        o += c0v * Wl[(4 * q + 0) * HID + f];
        o += c1v * Wl[(4 * q + 1) * HID + f];
        o += c2v * Wl[(4 * q + 2) * HID + f];
        o += c3v * Wl[(4 * q + 3) * HID + f];
    }
    if (lane < 32) y2[(size_t)n * 32 + f] = f2bf(o);
}

// ---------------- layer2 fused: agg + relu + dot -> sbuf ----------------
__global__ __launch_bounds__(256) void agg_mlp2_kernel(const ushort_t* __restrict__ y2,
                                                       const int* __restrict__ rowbeg,
                                                       const int* __restrict__ rowend,
                                                       const int* __restrict__ esrc,
                                                       const float* __restrict__ b2a,
                                                       const float* __restrict__ wc2,
                                                       const float* __restrict__ c0,
                                                       float* __restrict__ sbuf) {
    __shared__ float wcl[HID];
    __shared__ float b2l[HID];
    int t = threadIdx.x;
    if (t < HID) { wcl[t] = wc2[t]; b2l[t] = b2a[t]; }
    __syncthreads();

    int wv = t >> 6;
    int lane = t & 63;
    int grp = lane >> 3;
    int l = lane & 7;
    int n = blockIdx.x * 4 + wv;

    int beg = rowbeg[n], end = rowend[n];
    float ax0 = 0.f, ay0 = 0.f, az0 = 0.f, aw0 = 0.f;
    float ax1 = 0.f, ay1 = 0.f, az1 = 0.f, aw1 = 0.f;
    int p = beg + grp;
    for (; p + 8 < end; p += 16) {
        int s0 = esrc[p];
        int s1 = esrc[p + 8];
        ushort4 u0 = *(const ushort4*)&y2[(size_t)s0 * 32 + l * 4];
        ushort4 u1 = *(const ushort4*)&y2[(size_t)s1 * 32 + l * 4];
        ax0 += bf2f(u0.x); ay0 += bf2f(u0.y); az0 += bf2f(u0.z); aw0 += bf2f(u0.w);
        ax1 += bf2f(u1.x); ay1 += bf2f(u1.y); az1 += bf2f(u1.z); aw1 += bf2f(u1.w);
    }
    if (p < end) {
        ushort4 u0 = *(const ushort4*)&y2[(size_t)esrc[p] * 32 + l * 4];
        ax0 += bf2f(u0.x); ay0 += bf2f(u0.y); az0 += bf2f(u0.z); aw0 += bf2f(u0.w);
    }
    float vx = ax0 + ax1, vy = ay0 + ay1, vz = az0 + az1, vw = aw0 + aw1;
    vx += __shfl_xor(vx, 8, 64);  vy += __shfl_xor(vy, 8, 64);
    vz += __shfl_xor(vz, 8, 64);  vw += __shfl_xor(vw, 8, 64);
    vx += __shfl_xor(vx, 16, 64); vy += __shfl_xor(vy, 16, 64);
    vz += __shfl_xor(vz, 16, 64); vw += __shfl_xor(vw, 16, 64);
    vx += __shfl_xor(vx, 32, 64); vy += __shfl_xor(vy, 32, 64);
    vz += __shfl_xor(vz, 32, 64); vw += __shfl_xor(vw, 32, 64);

    ushort4 us = *(const ushort4*)&y2[(size_t)n * 32 + l * 4];
    float ux = vx + bf2f(us.x) + b2l[l * 4 + 0];
    float uy = vy + bf2f(us.y) + b2l[l * 4 + 1];
    float uz = vz + bf2f(us.z) + b2l[l * 4 + 2];
    float uw = vw + bf2f(us.w) + b2l[l * 4 + 3];
    ux = ux > 0.f ? ux : 0.f;
    uy = uy > 0.f ? uy : 0.f;
    uz = uz > 0.f ? uz : 0.f;
    uw = uw > 0.f ? uw : 0.f;

    float s = ux * wcl[l * 4 + 0] + uy * wcl[l * 4 + 1]
            + uz * wcl[l * 4 + 2] + uw * wcl[l * 4 + 3];
    s += __shfl_xor(s, 1, 64);
    s += __shfl_xor(s, 2, 64);
    s += __shfl_xor(s, 4, 64);
    if (lane == 0) sbuf[n] = s + *c0;
}

// ---------------- layer3: scalar aggregate ----------------
__global__ __launch_bounds__(256) void final_kernel(const float* __restrict__ sbuf,
                                                    const int* __restrict__ rowbeg,
                                                    const int* __restrict__ rowend,
                                                    const int* __restrict__ esrc,
                                                    const float* __restrict__ b3,
                                                    float* __restrict__ out) {
    int n = blockIdx.x * 256 + threadIdx.x;
    if (n >= NN) return;
    float v = sbuf[n] + b3[0];
    int beg = rowbeg[n], end = rowend[n];
    int p = beg;
    for (; p + 4 <= end; p += 4) {
        int s0 = esrc[p], s1 = esrc[p + 1], s2 = esrc[p + 2], s3 = esrc[p + 3];
        float g0 = sbuf[s0], g1 = sbuf[s1], g2 = sbuf[s2], g3 = sbuf[s3];
        v += g0; v += g1; v += g2; v += g3;
    }
    for (; p < end; p++) v += sbuf[esrc[p]];
    out[n] = v;
}

// ---------------- host ----------------
extern "C" void kernel_launch(void* const* d_in, const int* in_sizes, int n_in,
                              void* d_out, int out_size, void* d_ws, size_t ws_size,
                              hipStream_t stream) {
    const float* x   = (const float*)d_in[0];
    const void*  ei  = d_in[1];
    const float* w1a = (const float*)d_in[2];
    const float* b1a = (const float*)d_in[3];
    const float* w1b = (const float*)d_in[4];
    const float* b1b = (const float*)d_in[5];
    const float* w2a = (const float*)d_in[6];
    const float* b2a = (const float*)d_in[7];
    const float* w2b = (const float*)d_in[8];
    const float* b2b = (const float*)d_in[9];
    const float* w3  = (const float*)d_in[10];
    const float* b3  = (const float*)d_in[11];
    float* out = (float*)d_out;

    char* w = (char*)d_ws;
    ushort_t*     y1      = (ushort_t*)(w + 0);             //  6,400,000
    ushort_t*     y2      = (ushort_t*)(w + 6400000);       //  6,400,000
    int*          esrc    = (int*)     (w + 12800000);      //  8,007,680 (NB*BCAP*4)
    int*          rowbeg  = (int*)     (w + 20807680);      //    400,000
    int*          rowend  = (int*)     (w + 21207680);      //    400,000
    float*        sbuf    = (float*)   (w + 21607680);      //    400,000
    unsigned int* binned  = (unsigned int*)(w + 22007680);  //  8,007,680
    int*          gcursor = (int*)     (w + 30015360);      //      3,136
    int*          flag    = (int*)     (w + 30018496);      //         16
    float*        Wc      = (float*)   (w + 30018512);      //      4,096
    float*        bc1     = (float*)   (w + 30022608);      //        128
    float*        wc2     = (float*)   (w + 30022736);      //        128
    float*        c0      = (float*)   (w + 30022864);      //         16

    setup_kernel<<<2, 1024, 0, stream>>>(ei, w1b, b1b, w2a, w2b, b2b, w3,
                                         flag, gcursor, Wc, bc1, wc2, c0);
    proj_bin_kernel<<<NPJ + NBA, 256, 0, stream>>>(x, w1a, y1, ei, flag, gcursor, binned);
    bucket_csr_kernel<<<NB, 256, 0, stream>>>(binned, gcursor, rowbeg, rowend, esrc);
    agg_mlp1_kernel<<<NN / 4, 256, 0, stream>>>(y1, rowbeg, rowend, esrc, b1a, Wc, bc1, y2);
    agg_mlp2_kernel<<<NN / 4, 256, 0, stream>>>(y2, rowbeg, rowend, esrc, b2a, wc2, c0, sbuf);
    final_kernel<<<(NN + 255) / 256, 256, 0, stream>>>(sbuf, rowbeg, rowend, esrc, b3, out);
}

// Round 7
// 181.396 us; speedup vs baseline: 1.6980x; 1.0399x over previous
//
#include <hip/hip_runtime.h>

#define NN 100000
#define NE 1600000
#define IC 128
#define HID 32
#define NB 782           // buckets of 128 nodes
#define BCAP 2560        // padded bucket capacity (mean 2048, sigma~45 -> +11 sigma)
#define EB 4096          // edges per binning block
#define NBA 391          // ceil(NE/EB)
#define NPJ 1563         // ceil(NN/64) proj blocks

typedef unsigned short ushort_t;

__device__ __forceinline__ ushort_t f2bf(float x) {
    unsigned u = __float_as_uint(x);
    unsigned r = (u + 0x7fffu + ((u >> 16) & 1u)) >> 16;   // RNE
    return (ushort_t)r;
}
__device__ __forceinline__ float bf2f(ushort_t b) {
    return __uint_as_float(((unsigned)b) << 16);
}

__device__ __forceinline__ int edge_at(const void* ei, int i64f, long long idx) {
    return i64f ? (int)((const long long*)ei)[idx] : ((const int*)ei)[idx];
}

// ---------------- setup: detect dtype + precompute folded weights + zero cursors ----------------
__global__ __launch_bounds__(1024) void setup_kernel(const void* ei,
                                                     const float* __restrict__ w1b, const float* __restrict__ b1b,
                                                     const float* __restrict__ w2a, const float* __restrict__ w2b,
                                                     const float* __restrict__ b2b, const float* __restrict__ w3,
                                                     int* flag, int* gcursor,
                                                     float* Wc, float* bc1, float* wc2, float* c0) {
    int t = threadIdx.x;
    if (blockIdx.x == 1) {
        if (t < NB) gcursor[t] = 0;
        return;
    }
    if (t < 64) {
        const long long* p = (const long long*)ei;
        long long v = p[t];
        unsigned long long bad = __ballot(v < 0 || v >= NN);
        if (t == 0) *flag = (bad == 0ull) ? 1 : 0;
    }
    int k = t >> 5, j = t & 31;
    float acc = 0.f;
    for (int m = 0; m < HID; m++) acc += w1b[k * HID + m] * w2a[m * HID + j];
    Wc[k * HID + j] = acc;
    if (t < 32) {
        float a = 0.f;
        for (int m = 0; m < HID; m++) a += b1b[m] * w2a[m * HID + t];
        bc1[t] = a;
    } else if (t < 64) {
        int kk = t - 32;
        float a = 0.f;
        for (int jj = 0; jj < HID; jj++) a += w2b[kk * HID + jj] * w3[jj];
        wc2[kk] = a;
    } else if (t == 64) {
        float a = 0.f;
        for (int jj = 0; jj < HID; jj++) a += b2b[jj] * w3[jj];
        *c0 = a;
    }
}

// ---------------- proj1 + binscatter merged (independent work, concurrent blocks) ----------------
union SMU {
    struct { float xs[64 * 132]; float ws[IC * HID]; } pj;              // 50,176 B
    struct { int raws[EB]; int rawd[EB]; int h[NB]; int lcur[NB]; } bs; // 39,024 B
};

__global__ __launch_bounds__(256) void proj_bin_kernel(const float* __restrict__ x,
                                                       const float* __restrict__ w1a,
                                                       ushort_t* __restrict__ y1,
                                                       const void* ei, const int* flag,
                                                       int* gcursor,
                                                       unsigned int* __restrict__ binned) {
    __shared__ SMU sm;
    int t = threadIdx.x;

    if (blockIdx.x < NPJ) {
        int base = blockIdx.x * 64;
        #pragma unroll
        for (int i = 0; i < 16; i++) sm.pj.ws[i * 256 + t] = w1a[i * 256 + t];
        const float4* xg = (const float4*)x;
        #pragma unroll
        for (int i = 0; i < 8; i++) {
            int fi = i * 256 + t;
            int row = fi >> 5;
            int kq = fi & 31;
            float4 v = make_float4(0.f, 0.f, 0.f, 0.f);
            if (base + row < NN) v = xg[(size_t)(base + row) * 32 + kq];
            *(float4*)&sm.pj.xs[row * 132 + kq * 4] = v;
        }
        __syncthreads();

        int ng = t >> 3;
        int fg = t & 7;
        int n0 = ng * 2, n1 = n0 + 1;
        int j0 = fg * 4;
        float4 a0 = make_float4(0.f, 0.f, 0.f, 0.f);
        float4 a1 = make_float4(0.f, 0.f, 0.f, 0.f);
        #pragma unroll 8
        for (int k = 0; k < IC; k++) {
            float x0 = sm.pj.xs[n0 * 132 + k];
            float x1 = sm.pj.xs[n1 * 132 + k];
            float4 w = *(const float4*)&sm.pj.ws[k * HID + j0];
            a0.x += x0 * w.x; a0.y += x0 * w.y; a0.z += x0 * w.z; a0.w += x0 * w.w;
            a1.x += x1 * w.x; a1.y += x1 * w.y; a1.z += x1 * w.z; a1.w += x1 * w.w;
        }
        ushort4 p0, p1;
        p0.x = f2bf(a0.x); p0.y = f2bf(a0.y); p0.z = f2bf(a0.z); p0.w = f2bf(a0.w);
        p1.x = f2bf(a1.x); p1.y = f2bf(a1.y); p1.z = f2bf(a1.z); p1.w = f2bf(a1.w);
        if (base + n0 < NN) *(ushort4*)&y1[(size_t)(base + n0) * 32 + j0] = p0;
        if (base + n1 < NN) *(ushort4*)&y1[(size_t)(base + n1) * 32 + j0] = p1;
    } else {
        int bb = blockIdx.x - NPJ;
        for (int b = t; b < NB; b += 256) sm.bs.h[b] = 0;
        __syncthreads();
        int i64f = *flag;
        long long ebase = (long long)bb * EB;
        for (int i = t; i < EB; i += 256) {
            long long e = ebase + i;
            int s = 0, d = -1;
            if (e < NE) {
                s = edge_at(ei, i64f, e);
                d = edge_at(ei, i64f, NE + e);
                atomicAdd(&sm.bs.h[d >> 7], 1);
            }
            sm.bs.raws[i] = s;
            sm.bs.rawd[i] = d;
        }
        __syncthreads();
        for (int b = t; b < NB; b += 256)
            sm.bs.lcur[b] = sm.bs.h[b] ? atomicAdd(&gcursor[b], sm.bs.h[b]) : 0;
        __syncthreads();
        for (int i = t; i < EB; i += 256) {
            int d = sm.bs.rawd[i];
            if (d >= 0) {
                int b = d >> 7;
                int pos = atomicAdd(&sm.bs.lcur[b], 1);
                binned[(size_t)b * BCAP + pos] = ((unsigned)sm.bs.raws[i] << 7) | (unsigned)(d & 127);
            }
        }
    }
}

// ---------------- per-bucket CSR into padded esrc ----------------
__global__ __launch_bounds__(256) void bucket_csr_kernel(const unsigned int* __restrict__ binned,
                                                         const int* __restrict__ gcursor,
                                                         int* __restrict__ rowbeg,
                                                         int* __restrict__ rowend,
                                                         int* __restrict__ esrc) {
    __shared__ int cnt[128];
    __shared__ int sc[128];
    __shared__ int cur[128];
    int t = threadIdx.x;
    int b = blockIdx.x;
    int n = gcursor[b];
    int bbase = b * BCAP;
    if (t < 128) cnt[t] = 0;
    __syncthreads();
    for (int p = t; p < n; p += 256)
        atomicAdd(&cnt[binned[bbase + p] & 127], 1);
    __syncthreads();
    if (t < 128) sc[t] = cnt[t];
    __syncthreads();
    for (int off = 1; off < 128; off <<= 1) {
        int a = 0;
        if (t < 128 && t >= off) a = sc[t - off];
        __syncthreads();
        if (t < 128) sc[t] += a;
        __syncthreads();
    }
    if (t < 128) {
        int excl = sc[t] - cnt[t];
        int gn = (b << 7) + t;
        if (gn < NN) { rowbeg[gn] = bbase + excl; rowend[gn] = bbase + excl + cnt[t]; }
        cur[t] = excl;
    }
    __syncthreads();
    for (int p = t; p < n; p += 256) {
        unsigned w = binned[bbase + p];
        int dl = w & 127;
        int pos = bbase + atomicAdd(&cur[dl], 1);
        esrc[pos] = w >> 7;
    }
}

// ---------------- agg32: one-pass gather-sum of bf16[n][32] rows -> fp32 agg ----------------
// one wave per node; 8 groups of 8 lanes; lane loads ushort4 (8B) => 1 line per edge.
__global__ __launch_bounds__(256) void agg32_kernel(const ushort_t* __restrict__ y,
                                                    const int* __restrict__ rowbeg,
                                                    const int* __restrict__ rowend,
                                                    const int* __restrict__ esrc,
                                                    float* __restrict__ agg) {
    int t = threadIdx.x;
    int wv = t >> 6;
    int lane = t & 63;
    int grp = lane >> 3;      // 0..7
    int l = lane & 7;         // features 4l..4l+3
    int n = blockIdx.x * 4 + wv;       // NN divisible by 4

    int beg = rowbeg[n], end = rowend[n];
    float ax0 = 0.f, ay0 = 0.f, az0 = 0.f, aw0 = 0.f;
    float ax1 = 0.f, ay1 = 0.f, az1 = 0.f, aw1 = 0.f;
    int p = beg + grp;
    for (; p + 8 < end; p += 16) {
        int s0 = esrc[p];
        int s1 = esrc[p + 8];
        ushort4 u0 = *(const ushort4*)&y[(size_t)s0 * 32 + l * 4];
        ushort4 u1 = *(const ushort4*)&y[(size_t)s1 * 32 + l * 4];
        ax0 += bf2f(u0.x); ay0 += bf2f(u0.y); az0 += bf2f(u0.z); aw0 += bf2f(u0.w);
        ax1 += bf2f(u1.x); ay1 += bf2f(u1.y); az1 += bf2f(u1.z); aw1 += bf2f(u1.w);
    }
    if (p < end) {
        ushort4 u0 = *(const ushort4*)&y[(size_t)esrc[p] * 32 + l * 4];
        ax0 += bf2f(u0.x); ay0 += bf2f(u0.y); az0 += bf2f(u0.z); aw0 += bf2f(u0.w);
    }
    float vx = ax0 + ax1, vy = ay0 + ay1, vz = az0 + az1, vw = aw0 + aw1;
    vx += __shfl_xor(vx, 8, 64);  vy += __shfl_xor(vy, 8, 64);
    vz += __shfl_xor(vz, 8, 64);  vw += __shfl_xor(vw, 8, 64);
    vx += __shfl_xor(vx, 16, 64); vy += __shfl_xor(vy, 16, 64);
    vz += __shfl_xor(vz, 16, 64); vw += __shfl_xor(vw, 16, 64);
    vx += __shfl_xor(vx, 32, 64); vy += __shfl_xor(vy, 32, 64);
    vz += __shfl_xor(vz, 32, 64); vw += __shfl_xor(vw, 32, 64);
    if (lane < 8) {
        ushort4 us = *(const ushort4*)&y[(size_t)n * 32 + l * 4];   // self (eps=0)
        float4 o;
        o.x = vx + bf2f(us.x);
        o.y = vy + bf2f(us.y);
        o.z = vz + bf2f(us.z);
        o.w = vw + bf2f(us.w);
        *(float4*)&agg[(size_t)n * 32 + l * 4] = o;
    }
}

// ---------------- mlp1: y2 = relu(agg + b1a) @ Wc + bc1 -> bf16[n][32] ----------------
__global__ __launch_bounds__(256) void mlp1_kernel(const float* __restrict__ agg,
                                                   const float* __restrict__ b1a,
                                                   const float* __restrict__ Wc,
                                                   const float* __restrict__ bc1,
                                                   ushort_t* __restrict__ y2) {
    __shared__ float Wl[HID * HID];
    __shared__ float b1l[HID];
    __shared__ float bcl[HID];
    int t = threadIdx.x;
    #pragma unroll
    for (int i = 0; i < 4; i++) Wl[i * 256 + t] = Wc[i * 256 + t];
    if (t < HID) { b1l[t] = b1a[t]; bcl[t] = bc1[t]; }
    __syncthreads();

    int sub = t >> 5;
    int f = t & 31;
    int n = blockIdx.x * 8 + sub;      // NN divisible by 8

    float u = agg[(size_t)n * 32 + f] + b1l[f];
    u = u > 0.f ? u : 0.f;
    float o = bcl[f];
    #pragma unroll
    for (int k = 0; k < HID; k++)
        o += __shfl(u, k, 32) * Wl[k * HID + f];

    y2[(size_t)n * 32 + f] = f2bf(o);
}

// ---------------- mlp2: s = relu(agg + b2a) . wc2 + c0 ----------------
__global__ __launch_bounds__(256) void mlp2_kernel(const float* __restrict__ agg,
                                                   const float* __restrict__ b2a,
                                                   const float* __restrict__ wc2,
                                                   const float* __restrict__ c0,
                                                   float* __restrict__ sbuf) {
    __shared__ float wcl[HID];
    __shared__ float b2l[HID];
    int t = threadIdx.x;
    if (t < HID) { wcl[t] = wc2[t]; b2l[t] = b2a[t]; }
    __syncthreads();

    int sub = t >> 5;
    int f = t & 31;
    int n = blockIdx.x * 8 + sub;

    float u = agg[(size_t)n * 32 + f] + b2l[f];
    u = u > 0.f ? u : 0.f;
    float tt = u * wcl[f];
    #pragma unroll
    for (int off = 16; off > 0; off >>= 1) tt += __shfl_xor(tt, off, 32);
    if (f == 0) sbuf[n] = tt + *c0;
}

// ---------------- layer3: scalar aggregate ----------------
__global__ __launch_bounds__(256) void final_kernel(const float* __restrict__ sbuf,
                                                    const int* __restrict__ rowbeg,
                                                    const int* __restrict__ rowend,
                                                    const int* __restrict__ esrc,
                                                    const float* __restrict__ b3,
                                                    float* __restrict__ out) {
    int n = blockIdx.x * 256 + threadIdx.x;
    if (n >= NN) return;
    float v = sbuf[n] + b3[0];
    int beg = rowbeg[n], end = rowend[n];
    int p = beg;
    for (; p + 4 <= end; p += 4) {
        int s0 = esrc[p], s1 = esrc[p + 1], s2 = esrc[p + 2], s3 = esrc[p + 3];
        float g0 = sbuf[s0], g1 = sbuf[s1], g2 = sbuf[s2], g3 = sbuf[s3];
        v += g0; v += g1; v += g2; v += g3;
    }
    for (; p < end; p++) v += sbuf[esrc[p]];
    out[n] = v;
}

// ---------------- host ----------------
extern "C" void kernel_launch(void* const* d_in, const int* in_sizes, int n_in,
                              void* d_out, int out_size, void* d_ws, size_t ws_size,
                              hipStream_t stream) {
    const float* x   = (const float*)d_in[0];
    const void*  ei  = d_in[1];
    const float* w1a = (const float*)d_in[2];
    const float* b1a = (const float*)d_in[3];
    const float* w1b = (const float*)d_in[4];
    const float* b1b = (const float*)d_in[5];
    const float* w2a = (const float*)d_in[6];
    const float* b2a = (const float*)d_in[7];
    const float* w2b = (const float*)d_in[8];
    const float* b2b = (const float*)d_in[9];
    const float* w3  = (const float*)d_in[10];
    const float* b3  = (const float*)d_in[11];
    float* out = (float*)d_out;

    char* w = (char*)d_ws;
    ushort_t*     y1      = (ushort_t*)(w + 0);             //  6,400,000
    ushort_t*     y2      = (ushort_t*)(w + 6400000);       //  6,400,000
    int*          esrc    = (int*)     (w + 12800000);      //  8,007,680 (NB*BCAP*4)
    int*          rowbeg  = (int*)     (w + 20807680);      //    400,000
    int*          rowend  = (int*)     (w + 21207680);      //    400,000
    float*        sbuf    = (float*)   (w + 21607680);      //    400,000
    int*          gcursor = (int*)     (w + 22007680);      //      3,136
    int*          flag    = (int*)     (w + 22010816);      //         16
    float*        Wc      = (float*)   (w + 22010832);      //      4,096
    float*        bc1     = (float*)   (w + 22014928);      //        128
    float*        wc2     = (float*)   (w + 22015056);      //        128
    float*        c0      = (float*)   (w + 22015184);      //         48 (pad to 22015232)
    // binned (8.0 MB) overlays agg (12.8 MB fp32) — binned dead after bucket_csr
    unsigned int* binned  = (unsigned int*)(w + 22015232);
    float*        agg     = (float*)      (w + 22015232);   // ends at 34,815,232

    setup_kernel<<<2, 1024, 0, stream>>>(ei, w1b, b1b, w2a, w2b, b2b, w3,
                                         flag, gcursor, Wc, bc1, wc2, c0);
    proj_bin_kernel<<<NPJ + NBA, 256, 0, stream>>>(x, w1a, y1, ei, flag, gcursor, binned);
    bucket_csr_kernel<<<NB, 256, 0, stream>>>(binned, gcursor, rowbeg, rowend, esrc);

    agg32_kernel<<<NN / 4, 256, 0, stream>>>(y1, rowbeg, rowend, esrc, agg);
    mlp1_kernel<<<NN / 8, 256, 0, stream>>>(agg, b1a, Wc, bc1, y2);

    agg32_kernel<<<NN / 4, 256, 0, stream>>>(y2, rowbeg, rowend, esrc, agg);
    mlp2_kernel<<<NN / 8, 256, 0, stream>>>(agg, b2a, wc2, c0, sbuf);

    final_kernel<<<(NN + 255) / 256, 256, 0, stream>>>(sbuf, rowbeg, rowend, esrc, b3, out);
}